// Round 20
// baseline (768.178 us; speedup 1.0000x reference)
//
#include <hip/hip_runtime.h>
#include <hip/hip_fp16.h>

// Bidirectional char-LSTM + masked max-pool via MFMA — DUAL-DIRECTION block.
// 256 blocks = 256 chains; 1024 threads = 16 waves. Waves 0-7 run the FWD
// recurrence of chain b, waves 8-15 the BWD one: two INDEPENDENT dependency
// chains sharing one barrier/step. Each SIMD holds 2 fwd + 2 bwd waves ->
// latency of one chain hides under the other.
// R19 lesson (754us): amdgpu_num_vgpr(128) is NOT honored; heuristic gave
// 64 VGPR -> 96-reg weight array spilled 93 MB. Attribute ledger: plain
// __launch_bounds__ honors actual need up to the residency cap (R15: 108 no
// spill); cap for 1024-thread blocks = 512/4 = 128. R20 = R19 with plain
// __launch_bounds__(1024) + reg trims (~124 needed <= 128).
// Per half (= R15/R17 proven): CH=1, 16-dup acc cols; compact Hc[buf][half]
// [192] f16 read as broadcast b128 (conflict-free); role-split activation
// (DPP xor8, 6 trans/lane); single-copy dim-pair writeback (DPP xor1);
// 25-lane x staging. Bias rides MFMA: Hc[k=50] == 1.0, kt=1 weight frag
// carries (bih+bhh) at k==50.

#define TT 512

typedef _Float16 f16;
typedef _Float16 f16x8 __attribute__((ext_vector_type(8)));
typedef float f32x4 __attribute__((ext_vector_type(4)));
typedef unsigned int u32;
typedef unsigned short u16;

static __device__ __forceinline__ u32 packh2(float lo, float hi) {
    union { struct { f16 x, y; } h; u32 u; } cv;
    cv.h.x = (f16)lo; cv.h.y = (f16)hi;
    return cv.u;
}
static __device__ __forceinline__ float fexp(float x) {
    return __builtin_amdgcn_exp2f(x * 1.44269504088896341f);
}
static __device__ __forceinline__ float frcp(float x) {
    return __builtin_amdgcn_rcpf(x);
}
static __device__ __forceinline__ float sigf(float x) {
    return frcp(1.f + fexp(-x));
}
static __device__ __forceinline__ float xor8(float x) {
    // lane <-> lane^8: DPP row_ror:8 (rotate within rows of 16 == xor 8)
    union { float f; int i; } c; c.f = x;
    c.i = __builtin_amdgcn_mov_dpp(c.i, 0x128, 0xF, 0xF, false);
    return c.f;
}
static __device__ __forceinline__ float xor1(float x) {
    // lane <-> lane^1: quad_perm(1,0,3,2) = 0xB1
    union { float f; int i; } c; c.f = x;
    c.i = __builtin_amdgcn_mov_dpp(c.i, 0xB1, 0xF, 0xF, false);
    return c.f;
}
static __device__ __forceinline__ float sel4(f32x4 v, int q) {
    // q in 0..3, compile-time indices in each arm (no dynamic indexing)
    return (q & 2) ? ((q & 1) ? v[3] : v[2]) : ((q & 1) ? v[1] : v[0]);
}

__global__ __launch_bounds__(1024)
void bilstm_dual2_kernel(const int* __restrict__ idx,
                         const float* __restrict__ masks,
                         const float* __restrict__ emb,
                         const float* __restrict__ Wih_f, const float* __restrict__ Whh_f,
                         const float* __restrict__ bih_f, const float* __restrict__ bhh_f,
                         const float* __restrict__ Wih_b, const float* __restrict__ Whh_b,
                         const float* __restrict__ bih_b, const float* __restrict__ bhh_b,
                         float* __restrict__ out)
{
    // Hc[buf][half][k]: k 0..49 = x, k 50 = 1.0 (bias lane), 51..63 = 0 pad,
    // 64..191 = h[k-64].
    __shared__ __align__(16) u16 Hc[2][2][192];    // 1.5 KB
    __shared__ u16 idx16[TT];                      // 1 KB (same chain both halves)
    __shared__ u16 mbits[TT];                      // 1 KB

    const int tid  = threadIdx.x;
    const int lane = tid & 63;
    const int wv   = tid >> 6;        // wave 0..15
    const int half = wv >> 3;         // 0 = fwd, 1 = bwd (independent chains)
    const int wvh  = wv & 7;
    const int l15  = lane & 15;
    const int c4   = lane >> 4;       // 0..3 (acc row group / B k-group)
    const int b0   = blockIdx.x;      // chain 0..255
    const int rev  = half;

    const int q  = l15 & 3;           // acc row within c4 group (the dim)
    const bool rB = (l15 >> 3) != 0;  // role: A = state-owner, B = helper

    const float* Wih = half ? Wih_b : Wih_f;
    const float* Whh = half ? Whh_b : Whh_f;
    const float* bih = half ? bih_b : bih_f;
    const float* bhh = half ? bhh_b : bhh_f;

    // ---- init: idx (u16), mask bits, Hc = zeros except k==50 -> 1.0
    if (tid < TT) {
        idx16[tid] = (u16)idx[b0 * TT + tid];
        mbits[tid] = (masks[b0 * TT + tid] != 0.f) ? (u16)1 : (u16)0;
    }
    if (tid < 384) {                       // 2 buf x 2 half x 96 u32
        const int kpair = (tid % 96) * 2;  // element index of the low half
        ((u32*)Hc)[tid] = (kpair == 50) ? 0x00003C00u : 0u;  // f16 1.0 at k=50
    }

    // ---- W fragments (A-operand) in VGPRs: w[kt][gt], gt = i/f/g/o.
    // Lane provides A[row = gate][k]: gate n = (wvh + gt*8)*16 + l15,
    // k = kt*32 + c4*8 + j, j = 0..7. kt=1 embeds bias at k==50.
    f16x8 w[6][4];
#pragma unroll
    for (int gt = 0; gt < 4; ++gt) {
        const int n = (wvh + gt * 8) * 16 + l15;
        // kt = 0: k = c4*8 + j (< 32 < 50) -> Wih (float2 loads)
#pragma unroll
        for (int jj = 0; jj < 4; ++jj) {
            const float2 e = *(const float2*)(Wih + n * 50 + c4 * 8 + jj * 2);
            w[0][gt][2 * jj]     = (f16)e.x;
            w[0][gt][2 * jj + 1] = (f16)e.y;
        }
        // kt = 1: k = 32 + c4*8 + j; k<50 -> Wih; k==50 -> bias; else 0
#pragma unroll
        for (int j = 0; j < 8; ++j) {
            const int k = 32 + c4 * 8 + j;
            float v = 0.f;
            if (k < 50)       v = Wih[n * 50 + k];
            else if (k == 50) v = bih[n] + bhh[n];
            w[1][gt][j] = (f16)v;
        }
        // kt = 2..5: k >= 64 -> Whh[n][k-64] (16B aligned float4 x2)
#pragma unroll
        for (int kt = 2; kt < 6; ++kt) {
            const int kh = (kt - 2) * 32 + c4 * 8;
            const float4 e0 = *(const float4*)(Whh + n * 128 + kh);
            const float4 e1 = *(const float4*)(Whh + n * 128 + kh + 4);
            w[kt][gt][0] = (f16)e0.x; w[kt][gt][1] = (f16)e0.y;
            w[kt][gt][2] = (f16)e0.z; w[kt][gt][3] = (f16)e0.w;
            w[kt][gt][4] = (f16)e1.x; w[kt][gt][5] = (f16)e1.y;
            w[kt][gt][6] = (f16)e1.z; w[kt][gt][7] = (f16)e1.w;
        }
    }

    __syncthreads();   // idx16/mbits/Hc init visible before x store

    // ---- x staging: wave wvh==7 of each half, lanes 0..24 (25 half-pairs)
    const bool xthr = (wvh == 7) && (lane < 25);

    if (xthr) {
        const int t0  = rev ? (TT - 1) : 0;
        const float2 e = *(const float2*)(emb + (int)idx16[t0] * 50 + lane * 2);
        *(u32*)((unsigned char*)&Hc[0][half][0] + lane * 4) = packh2(e.x, e.y);
    }
    __syncthreads();

    float cst = 0.f, rm = -3e38f;
    const int hd = wvh * 16 + c4 * 4 + q;   // this lane's dim

    for (int s = 0; s < TT; ++s) {
        const int cur = s & 1;
        const int t   = rev ? (TT - 1 - s) : s;

        // prefetch next step's x pair; pack to u32 immediately (reg trim)
        u32 epk = 0;
        const bool pf = xthr && (s + 1 < TT);
        if (pf) {
            const int t1  = rev ? (TT - 2 - s) : (s + 1);
            const float2 e = *(const float2*)(emb + (int)idx16[t1] * 50 + lane * 2);
            epk = packh2(e.x, e.y);
        }

        // ---- MFMA: 4 gate tiles x 6 K-steps; B-frag = broadcast b128 read
        const unsigned char* hb = (const unsigned char*)&Hc[cur][half][0];
        const f32x4 z = {0.f, 0.f, 0.f, 0.f};
        f32x4 ai = z, af = z, ag = z, ao = z;   // bias comes via k==50
#pragma unroll
        for (int kt = 0; kt < 6; ++kt) {
            const f16x8 bf = *(const f16x8*)(hb + kt * 64 + c4 * 16);
            ai = __builtin_amdgcn_mfma_f32_16x16x32_f16(w[kt][0], bf, ai, 0, 0, 0);
            af = __builtin_amdgcn_mfma_f32_16x16x32_f16(w[kt][1], bf, af, 0, 0, 0);
            ag = __builtin_amdgcn_mfma_f32_16x16x32_f16(w[kt][2], bf, ag, 0, 0, 0);
            ao = __builtin_amdgcn_mfma_f32_16x16x32_f16(w[kt][3], bf, ao, 0, 0, 0);
        }

        // ---- q-row select (cols 16x duplicated -> all lanes valid)
        const float iv = sel4(ai, q);
        const float fv = sel4(af, q);
        const float gv = sel4(ag, q);
        const float ov = sel4(ao, q);

        // ---- SIMT role-split activation, DPP transport (R13-R17 proven):
        // role A: su=sig(f), sv=sig(i); role B: su=sig(2g), sv=sig(o)
        const float u_in = rB ? (gv + gv) : fv;
        const float v_in = rB ? ov : iv;
        const float su = sigf(u_in);
        const float sv = sigf(v_in);
        const float tg_send = 2.f * su - 1.f;     // B: tanh(g); A: junk
        const float tgx = xor8(tg_send);          // A receives tanh(g)
        const float svx = xor8(sv);               // A receives sig(o)
        const float cc = su * cst + sv * tgx;     // A: valid c; B: junk chain
        cst = cc;
        const float ccx = xor8(cc);               // B receives A's cc
        const float cc_use = rB ? ccx : cc;
        const float th = 2.f * sigf(cc_use + cc_use) - 1.f;   // tanh(c)
        const float so_use = rB ? sv : svx;       // sig(o) in both roles
        const float hh = so_use * th;             // VALID in all lanes

        const float pen = mbits[t] ? 0.f : 1e8f;
        rm = fmaxf(rm, hh - pen);

        // ---- writeback: single copy, dim-pair packed via DPP xor1
        unsigned char* nb = (unsigned char*)&Hc[cur ^ 1][half][0];
        const float hx = xor1(hh);                // neighbor dim's h (q^1)
        if (l15 == 0 || l15 == 2) {
            // q even: pk = (h[hd], h[hd+1]); byte 128 + hd*2 is 4B-aligned
            *(u32*)(nb + 128 + hd * 2) = packh2(hh, hx);
        }
        if (pf) {
            *(u32*)(nb + lane * 4) = epk;
        }
        __syncthreads();
    }

    // ---- output: lanes l15 < 4 (q = l15) -> unique dim per lane
    if (l15 < 4) {
        out[b0 * 256 + half * 128 + hd] = rm;
    }
}

extern "C" void kernel_launch(void* const* d_in, const int* in_sizes, int n_in,
                              void* d_out, int out_size, void* d_ws, size_t ws_size,
                              hipStream_t stream) {
    const int*   idx   = (const int*)d_in[0];
    const float* masks = (const float*)d_in[1];
    const float* emb   = (const float*)d_in[2];
    const float* Wih_f = (const float*)d_in[3];
    const float* Whh_f = (const float*)d_in[4];
    const float* bih_f = (const float*)d_in[5];
    const float* bhh_f = (const float*)d_in[6];
    const float* Wih_b = (const float*)d_in[7];
    const float* Whh_b = (const float*)d_in[8];
    const float* bih_b = (const float*)d_in[9];
    const float* bhh_b = (const float*)d_in[10];
    float* out = (float*)d_out;

    bilstm_dual2_kernel<<<dim3(256), dim3(1024), 0, stream>>>(
        idx, masks, emb,
        Wih_f, Whh_f, bih_f, bhh_f,
        Wih_b, Whh_b, bih_b, bhh_b,
        out);
}

// Round 21
// 724.862 us; speedup vs baseline: 1.0598x; 1.0598x over previous
//
#include <hip/hip_runtime.h>
#include <hip/hip_fp16.h>

// Bidirectional char-LSTM + masked max-pool via MFMA — VOCAB-XG PRECOMPUTE.
// Kernel 1: xe[dir][10000][512] = emb . Wih^T + (bih+bhh), f16, into d_ws
//   (20.5 MB; 1 GFLOP; unit-ordered so the recurrent kernel's acc-init is
//   4x 8B gathers per lane).
// Kernel 2: recurrent loop = R17 structure with K=192 -> 128:
//   weights 96 -> 64 VGPR (Whh only), MFMA 24 -> 16/wave, ds_read 6 -> 4,
//   x-staging/emb path GONE from the loop; acc initialized from prefetched
//   xe rows. Per-wave regs ~103 (+16 acc) -> 2 blocks/CU possible.
//   256 blocks = 2 dirs x 128 chain-pairs, 512 thr, compact Hc (broadcast
//   b128), role-split activation (DPP xor8), pair-packed writeback (xor1),
//   one barrier/step.
// R20 lesson closed: 1024-thr blocks always get 64 VGPR (spill); only
// 512-thr blocks honor ~110. Shrinking weights is the only path forward.
// Fallback: if ws_size < 20.5 MB, launch the R17 kernel (381 us).

#define TT 512
#define CH 2
#define XE_U16 (2 * 10000 * 512)

typedef _Float16 f16;
typedef _Float16 f16x8 __attribute__((ext_vector_type(8)));
typedef float f32x4 __attribute__((ext_vector_type(4)));
typedef unsigned int u32;
typedef unsigned short u16;

static __device__ __forceinline__ u32 packh2(float lo, float hi) {
    union { struct { f16 x, y; } h; u32 u; } cv;
    cv.h.x = (f16)lo; cv.h.y = (f16)hi;
    return cv.u;
}
static __device__ __forceinline__ u16 f16bits(float v) {
    union { f16 h; u16 u; } cv; cv.h = (f16)v; return cv.u;
}
static __device__ __forceinline__ float fexp(float x) {
    return __builtin_amdgcn_exp2f(x * 1.44269504088896341f);
}
static __device__ __forceinline__ float frcp(float x) {
    return __builtin_amdgcn_rcpf(x);
}
static __device__ __forceinline__ float sigf(float x) {
    return frcp(1.f + fexp(-x));
}
static __device__ __forceinline__ float xor8(float x) {
    union { float f; int i; } c; c.f = x;
    c.i = __builtin_amdgcn_mov_dpp(c.i, 0x128, 0xF, 0xF, false);
    return c.f;
}
static __device__ __forceinline__ float xor2(float x) {
    union { float f; int i; } c; c.f = x;
    c.i = __builtin_amdgcn_mov_dpp(c.i, 0x4E, 0xF, 0xF, false);
    return c.f;
}
static __device__ __forceinline__ float sel4(f32x4 v, int q) {
    return (q & 2) ? ((q & 1) ? v[3] : v[2]) : ((q & 1) ? v[1] : v[0]);
}
static __device__ __forceinline__ f32x4 cvt4(uint2 u) {
    union { uint2 u2; f16 h[4]; } cv; cv.u2 = u;
    f32x4 r;
    r[0] = (float)cv.h[0]; r[1] = (float)cv.h[1];
    r[2] = (float)cv.h[2]; r[3] = (float)cv.h[3];
    return r;
}

// ---------------- Kernel 1: xe precompute ----------------
// grid 20000 = dir*10000 + v; 128 threads; thread U computes 4 gates
// g = (wv + gt*8)*16 + c4*4 + q (wv=U>>4, gt=(U>>2)&3, c4=U&3) and writes
// one 8B f16x4 unit at xe[(dir*10000+v)*512 + U*4].
__global__ __launch_bounds__(128)
void xe_precompute_kernel(const float* __restrict__ emb,
                          const float* __restrict__ Wih_f,
                          const float* __restrict__ bih_f, const float* __restrict__ bhh_f,
                          const float* __restrict__ Wih_b,
                          const float* __restrict__ bih_b, const float* __restrict__ bhh_b,
                          u16* __restrict__ xe)
{
    const int v    = blockIdx.x % 10000;
    const int ddir = blockIdx.x / 10000;
    const float* Wih = ddir ? Wih_b : Wih_f;
    const float* bih = ddir ? bih_b : bih_f;
    const float* bhh = ddir ? bhh_b : bhh_f;

    __shared__ float xrow[50];
    const int tid = threadIdx.x;
    if (tid < 50) xrow[tid] = emb[v * 50 + tid];
    __syncthreads();

    const int wv = tid >> 4, gt = (tid >> 2) & 3, c4 = tid & 3;
    const int g0 = (wv + gt * 8) * 16 + c4 * 4;

    float a[4];
#pragma unroll
    for (int q = 0; q < 4; ++q) {
        const float* wr = Wih + (g0 + q) * 50;   // 50*4B stride -> 8B aligned
        float acc = bih[g0 + q] + bhh[g0 + q];
#pragma unroll
        for (int kk = 0; kk < 25; ++kk) {
            const float2 w2 = *(const float2*)(wr + kk * 2);
            acc += xrow[2 * kk] * w2.x + xrow[2 * kk + 1] * w2.y;
        }
        a[q] = acc;
    }
    u16* dst = xe + (ddir * 10000 + v) * 512 + tid * 4;
    dst[0] = f16bits(a[0]); dst[1] = f16bits(a[1]);
    dst[2] = f16bits(a[2]); dst[3] = f16bits(a[3]);
}

// ---------------- Kernel 2: recurrent loop (K = 128) ----------------
__global__ __launch_bounds__(512)
void bilstm_xe_kernel(const int* __restrict__ idx,
                      const float* __restrict__ masks,
                      const u16* __restrict__ xe,
                      const float* __restrict__ Whh_f,
                      const float* __restrict__ Whh_b,
                      float* __restrict__ out)
{
    // Hc[buf][chain][k]: k 0..127 = h (pure h state, x lives in acc init)
    __shared__ __align__(16) u16 Hc[2][CH][128];   // 1 KB
    __shared__ u16 idx16[CH * TT];                 // 2 KB
    __shared__ u32 mbits[TT];                      // 2 KB

    const int tid  = threadIdx.x;
    const int lane = tid & 63;
    const int wv   = tid >> 6;        // wave 0..7
    const int l15  = lane & 15;
    const int c4   = lane >> 4;       // 0..3
    const int d    = blockIdx.x & 1;  // 0 fwd, 1 bwd
    const int g    = blockIdx.x >> 1; // 0..127
    const int b0   = g * CH;
    const int rev  = d;

    const int chain = l15 & 1;
    const int q     = (l15 >> 1) & 3;
    const bool rB   = (l15 >> 3) != 0;

    const float* Whh = d ? Whh_b : Whh_f;

    // ---- init: idx (u16), mask bits, zero Hc
    for (int i = tid; i < CH * TT; i += 512) {
        const int m = i >> 9, t = i & 511;
        idx16[i] = (u16)idx[(b0 + m) * TT + t];
    }
    if (tid < TT) {
        u32 mb = 0;
        for (int m = 0; m < CH; ++m)
            mb |= (masks[(b0 + m) * TT + tid] != 0.f ? 1u : 0u) << m;
        mbits[tid] = mb;
    }
    if (tid < 2 * CH * 128 / 2) {          // 256 u32s
        ((u32*)Hc)[tid] = 0u;
    }

    // ---- Whh fragments (A-operand): w[kt][gt], kt = 0..3 covers k 0..127.
    // Lane provides A[row = gate][k]: gate n = (wv + gt*8)*16 + l15,
    // k = kt*32 + c4*8 + j, j = 0..7.
    f16x8 w[4][4];
#pragma unroll
    for (int gt = 0; gt < 4; ++gt) {
        const int n = (wv + gt * 8) * 16 + l15;
#pragma unroll
        for (int kt = 0; kt < 4; ++kt) {
            const int kh = kt * 32 + c4 * 8;
            const float4 e0 = *(const float4*)(Whh + n * 128 + kh);
            const float4 e1 = *(const float4*)(Whh + n * 128 + kh + 4);
            w[kt][gt][0] = (f16)e0.x; w[kt][gt][1] = (f16)e0.y;
            w[kt][gt][2] = (f16)e0.z; w[kt][gt][3] = (f16)e0.w;
            w[kt][gt][4] = (f16)e1.x; w[kt][gt][5] = (f16)e1.y;
            w[kt][gt][6] = (f16)e1.z; w[kt][gt][7] = (f16)e1.w;
        }
    }

    __syncthreads();   // idx16/mbits/Hc-zero visible

    // ---- xe gather address pieces: unit U = wv*16 + gt*4 + c4, 8B each
    const int ubase = (wv * 16 + c4) * 4;      // u16 offset of gt=0 unit
    const int xrowmul = 512;                   // u16 per xe row
    const int xdbase = d * 10000 * 512;

    // ---- prefetch xw for step 0
    uint2 xw0, xw1, xw2, xw3;
    {
        const int t0  = rev ? (TT - 1) : 0;
        const int row = idx16[chain * TT + t0];
        const u16* rb = xe + xdbase + row * xrowmul + ubase;
        xw0 = *(const uint2*)(rb);
        xw1 = *(const uint2*)(rb + 16);
        xw2 = *(const uint2*)(rb + 32);
        xw3 = *(const uint2*)(rb + 48);
    }

    float cst = 0.f, rm = -3e38f;
    const int hd = wv * 16 + c4 * 4 + q;   // this lane's dim
    const bool wbthr = (l15 == 0) | (l15 == 1) | (l15 == 4) | (l15 == 5);

    for (int s = 0; s < TT; ++s) {
        const int cur = s & 1;
        const int t   = rev ? (TT - 1 - s) : s;

        // acc init = xg(t) for this lane's 16 (gate, q) slots
        f32x4 ai = cvt4(xw0), af = cvt4(xw1), ag = cvt4(xw2), ao = cvt4(xw3);

        // prefetch next step's xe units (hidden under MFMA; L2/L3 resident)
        const bool pf = (s + 1 < TT);
        if (pf) {
            const int t1  = rev ? (TT - 2 - s) : (s + 1);
            const int row = idx16[chain * TT + t1];
            const u16* rb = xe + xdbase + row * xrowmul + ubase;
            xw0 = *(const uint2*)(rb);
            xw1 = *(const uint2*)(rb + 16);
            xw2 = *(const uint2*)(rb + 32);
            xw3 = *(const uint2*)(rb + 48);
        }

        // ---- MFMA: 4 gate tiles x 4 K-steps; B-frag = broadcast b128 read
        const unsigned char* hb =
            (const unsigned char*)&Hc[cur][0][0] + chain * 256;
#pragma unroll
        for (int kt = 0; kt < 4; ++kt) {
            const f16x8 bf = *(const f16x8*)(hb + kt * 64 + c4 * 16);
            ai = __builtin_amdgcn_mfma_f32_16x16x32_f16(w[kt][0], bf, ai, 0, 0, 0);
            af = __builtin_amdgcn_mfma_f32_16x16x32_f16(w[kt][1], bf, af, 0, 0, 0);
            ag = __builtin_amdgcn_mfma_f32_16x16x32_f16(w[kt][2], bf, ag, 0, 0, 0);
            ao = __builtin_amdgcn_mfma_f32_16x16x32_f16(w[kt][3], bf, ao, 0, 0, 0);
        }

        // ---- q-row select
        const float iv = sel4(ai, q);
        const float fv = sel4(af, q);
        const float gv = sel4(ag, q);
        const float ov = sel4(ao, q);

        // ---- role-split activation, DPP transport (proven R13-R17)
        const float u_in = rB ? (gv + gv) : fv;
        const float v_in = rB ? ov : iv;
        const float su = sigf(u_in);
        const float sv = sigf(v_in);
        const float tg_send = 2.f * su - 1.f;
        const float tgx = xor8(tg_send);
        const float svx = xor8(sv);
        const float cc = su * cst + sv * tgx;
        cst = cc;
        const float ccx = xor8(cc);
        const float cc_use = rB ? ccx : cc;
        const float th = 2.f * sigf(cc_use + cc_use) - 1.f;
        const float so_use = rB ? sv : svx;
        const float hh = so_use * th;

        const float pen = ((mbits[t] >> chain) & 1u) ? 0.f : 1e8f;
        rm = fmaxf(rm, hh - pen);

        // ---- writeback: single copy, dim-pair packed via DPP xor2
        unsigned char* nb = (unsigned char*)&Hc[cur ^ 1][0][0];
        const float hx2 = xor2(hh);
        if (wbthr) {
            *(u32*)(nb + chain * 256 + hd * 2) = packh2(hh, hx2);
        }
        __syncthreads();
    }

    if (l15 < 8) {
        out[(b0 + chain) * 256 + d * 128 + hd] = rm;
    }
}

// ---------------- Fallback: R17 kernel (381 us), used if ws too small ----
__global__ __attribute__((amdgpu_flat_work_group_size(512, 512),
                          amdgpu_waves_per_eu(2, 2)))
void bilstm_compact_kernel(const int* __restrict__ idx,
                           const float* __restrict__ masks,
                           const float* __restrict__ emb,
                           const float* __restrict__ Wih_f, const float* __restrict__ Whh_f,
                           const float* __restrict__ bih_f, const float* __restrict__ bhh_f,
                           const float* __restrict__ Wih_b, const float* __restrict__ Whh_b,
                           const float* __restrict__ bih_b, const float* __restrict__ bhh_b,
                           float* __restrict__ out)
{
    __shared__ __align__(16) u16 Hc[2][CH][192];
    __shared__ u16 idx16[CH * TT];
    __shared__ u32 mbits[TT];

    const int tid  = threadIdx.x;
    const int lane = tid & 63;
    const int wv   = tid >> 6;
    const int l15  = lane & 15;
    const int c4   = lane >> 4;
    const int d    = blockIdx.x & 1;
    const int g    = blockIdx.x >> 1;
    const int b0   = g * CH;
    const int rev  = d;
    const int chain = l15 & 1;
    const int q     = (l15 >> 1) & 3;
    const int role  = l15 >> 3;

    const float* Wih = d ? Wih_b : Wih_f;
    const float* Whh = d ? Whh_b : Whh_f;
    const float* bih = d ? bih_b : bih_f;
    const float* bhh = d ? bhh_b : bhh_f;

    for (int i = tid; i < CH * TT; i += 512) {
        const int m = i >> 9, t = i & 511;
        idx16[i] = (u16)idx[(b0 + m) * TT + t];
    }
    if (tid < TT) {
        u32 mb = 0;
        for (int m = 0; m < CH; ++m)
            mb |= (masks[(b0 + m) * TT + tid] != 0.f ? 1u : 0u) << m;
        mbits[tid] = mb;
    }
    if (tid < 2 * CH * 192 / 2) ((u32*)Hc)[tid] = 0u;

    f16x8 w[6][4];
    f32x4 bias4[4];
#pragma unroll
    for (int gt = 0; gt < 4; ++gt) {
        const int n = (wv + gt * 8) * 16 + l15;
        {
            const int nb_ = (wv + gt * 8) * 16 + c4 * 4;
            const float4 bi = *(const float4*)(bih + nb_);
            const float4 bh = *(const float4*)(bhh + nb_);
            bias4[gt][0] = bi.x + bh.x; bias4[gt][1] = bi.y + bh.y;
            bias4[gt][2] = bi.z + bh.z; bias4[gt][3] = bi.w + bh.w;
        }
#pragma unroll
        for (int jj = 0; jj < 4; ++jj) {
            const float2 e = *(const float2*)(Wih + n * 50 + c4 * 8 + jj * 2);
            w[0][gt][2 * jj]     = (f16)e.x;
            w[0][gt][2 * jj + 1] = (f16)e.y;
        }
#pragma unroll
        for (int j = 0; j < 8; ++j) {
            const int k = 32 + c4 * 8 + j;
            float v = 0.f;
            if (k < 50) v = Wih[n * 50 + k];
            w[1][gt][j] = (f16)v;
        }
#pragma unroll
        for (int kt = 2; kt < 6; ++kt) {
            const int kh = (kt - 2) * 32 + c4 * 8;
            const float4 e0 = *(const float4*)(Whh + n * 128 + kh);
            const float4 e1 = *(const float4*)(Whh + n * 128 + kh + 4);
            w[kt][gt][0] = (f16)e0.x; w[kt][gt][1] = (f16)e0.y;
            w[kt][gt][2] = (f16)e0.z; w[kt][gt][3] = (f16)e0.w;
            w[kt][gt][4] = (f16)e1.x; w[kt][gt][5] = (f16)e1.y;
            w[kt][gt][6] = (f16)e1.z; w[kt][gt][7] = (f16)e1.w;
        }
    }
    __syncthreads();

    const int  tid7 = tid - 448;
    const bool xthr = (tid7 >= 0) && (tid7 < 50);
    const int  xch  = xthr ? (tid7 / 25) : 0;
    const int  xps  = xthr ? (tid7 % 25) : 0;
    if (xthr) {
        const int t0  = rev ? (TT - 1) : 0;
        const int row = idx16[xch * TT + t0];
        const float2 e = *(const float2*)(emb + row * 50 + xps * 2);
        *(u32*)((unsigned char*)&Hc[0][0][0] + xch * 384 + xps * 4) =
            packh2(e.x, e.y);
    }
    __syncthreads();

    float cst = 0.f, rm = -3e38f;
    const int hd = wv * 16 + c4 * 4 + q;
    const bool wbthr = (l15 == 0) | (l15 == 1) | (l15 == 4) | (l15 == 5);

    for (int s = 0; s < TT; ++s) {
        const int cur = s & 1;
        const int t   = rev ? (TT - 1 - s) : s;
        float2 e;
        const bool pf = xthr && (s + 1 < TT);
        if (pf) {
            const int t1  = rev ? (TT - 2 - s) : (s + 1);
            const int row = idx16[xch * TT + t1];
            e = *(const float2*)(emb + row * 50 + xps * 2);
        }
        const unsigned char* hb =
            (const unsigned char*)&Hc[cur][0][0] + chain * 384;
        f32x4 ai = bias4[0], af = bias4[1], ag = bias4[2], ao = bias4[3];
#pragma unroll
        for (int kt = 0; kt < 6; ++kt) {
            const f16x8 bf = *(const f16x8*)(hb + kt * 64 + c4 * 16);
            ai = __builtin_amdgcn_mfma_f32_16x16x32_f16(w[kt][0], bf, ai, 0, 0, 0);
            af = __builtin_amdgcn_mfma_f32_16x16x32_f16(w[kt][1], bf, af, 0, 0, 0);
            ag = __builtin_amdgcn_mfma_f32_16x16x32_f16(w[kt][2], bf, ag, 0, 0, 0);
            ao = __builtin_amdgcn_mfma_f32_16x16x32_f16(w[kt][3], bf, ao, 0, 0, 0);
        }
        const float iv = sel4(ai, q);
        const float fv = sel4(af, q);
        const float gv = sel4(ag, q);
        const float ov = sel4(ao, q);
        const bool rB = (role != 0);
        const float u_in = rB ? (gv + gv) : fv;
        const float v_in = rB ? ov : iv;
        const float su = sigf(u_in);
        const float sv = sigf(v_in);
        const float tg_send = 2.f * su - 1.f;
        const float tgx = xor8(tg_send);
        const float svx = xor8(sv);
        const float cc = su * cst + sv * tgx;
        cst = cc;
        const float ccx = xor8(cc);
        const float cc_use = rB ? ccx : cc;
        const float th = 2.f * sigf(cc_use + cc_use) - 1.f;
        const float so_use = rB ? sv : svx;
        const float hh = so_use * th;
        const float pen = ((mbits[t] >> chain) & 1u) ? 0.f : 1e8f;
        rm = fmaxf(rm, hh - pen);
        unsigned char* nb = (unsigned char*)&Hc[cur ^ 1][0][0];
        const float hx2 = xor2(hh);
        if (wbthr) {
            *(u32*)(nb + chain * 384 + 128 + hd * 2) = packh2(hh, hx2);
        }
        if (pf) {
            *(u32*)(nb + xch * 384 + xps * 4) = packh2(e.x, e.y);
        }
        __syncthreads();
    }
    if (l15 < 8) {
        out[(b0 + chain) * 256 + d * 128 + hd] = rm;
    }
}

extern "C" void kernel_launch(void* const* d_in, const int* in_sizes, int n_in,
                              void* d_out, int out_size, void* d_ws, size_t ws_size,
                              hipStream_t stream) {
    const int*   idx   = (const int*)d_in[0];
    const float* masks = (const float*)d_in[1];
    const float* emb   = (const float*)d_in[2];
    const float* Wih_f = (const float*)d_in[3];
    const float* Whh_f = (const float*)d_in[4];
    const float* bih_f = (const float*)d_in[5];
    const float* bhh_f = (const float*)d_in[6];
    const float* Wih_b = (const float*)d_in[7];
    const float* Whh_b = (const float*)d_in[8];
    const float* bih_b = (const float*)d_in[9];
    const float* bhh_b = (const float*)d_in[10];
    float* out = (float*)d_out;

    const size_t xe_bytes = (size_t)XE_U16 * sizeof(u16);   // 20.48 MB
    if (ws_size >= xe_bytes) {
        u16* xe = (u16*)d_ws;
        xe_precompute_kernel<<<dim3(20000), dim3(128), 0, stream>>>(
            emb, Wih_f, bih_f, bhh_f, Wih_b, bih_b, bhh_b, xe);
        bilstm_xe_kernel<<<dim3(256), dim3(512), 0, stream>>>(
            idx, masks, xe, Whh_f, Whh_b, out);
    } else {
        bilstm_compact_kernel<<<dim3(256), dim3(512), 0, stream>>>(
            idx, masks, emb,
            Wih_f, Whh_f, bih_f, bhh_f,
            Wih_b, Whh_b, bih_b, bhh_b,
            out);
    }
}